// Round 10
// baseline (36.644 us; speedup 1.0000x reference)
//
#include <hip/hip_runtime.h>

#define NB 4
#define NC 32
#define H0 64
#define W0 128
#define D0 12
#define H1 128
#define W1 256
#define NK 5
#define IMH 512
#define IMW 1024

#define S0L 88    // frs0 stride: 21 f4 data + pad; 88%32=24 -> exact 2-way (free)
#define S1L 168   // frs1 stride: 40 f4 data + pad; 168%32=8 -> exact 2-way (free)

// ---------------------------------------------------------------------------
// K1: block = (b, m, xh). Recomputes pl0 rows m-1..m+1 for its 65-col span,
// exact 3x3 wflow composite, residual cost for oy=2m..2m+1, ox half xh.
// Barrier-free fusion (3 __syncthreads, no grid sync). 77.3 KB LDS -> 2/CU.
// ---------------------------------------------------------------------------
__global__ __launch_bounds__(512, 4) void k_main(
        const float* __restrict__ fl0, const float* __restrict__ fr0,
        const float* __restrict__ fl1, const float* __restrict__ fr1,
        float* __restrict__ pl0, float* __restrict__ pl1) {
    const int bk = blockIdx.x;           // 0..511
    const int xh = bk & 1;
    const int mb = bk >> 1;              // b*H0 + m
    const int b = mb >> 6, m = mb & 63;
    const int tid = threadIdx.x;         // 0..511

    __shared__ float frs0[3][NC][S0L];   // 33 KB
    __shared__ float frs1[2][NC][S1L];   // 42 KB
    __shared__ float p0l[3][65];
    __shared__ float ytmp[2][65];
    __shared__ float wfl[2][128];

    const int colp = xh * 63;            // pl0 col base (65 cols: colp..colp+64)
    const int s0c0 = xh * 64 - 16;       // frs0 staged col 0
    const int s1c0 = xh * 128 - 28;      // frs1 staged col 0

    // ---- stage fr0: 3 rows x 32 ch x 22 float4 (zero OOB) ----
#pragma unroll
    for (int i = 0; i < 5; ++i) {
        int idx = i * 512 + tid;
        if (idx < 2112) {
            int rr = idx / 704, rem = idx - rr * 704;
            int c = rem / 22, q = rem - c * 22;
            int row = min(max(m - 1 + rr, 0), H0 - 1);
            int colg = s0c0 + 4 * q;
            float4 v = make_float4(0.f, 0.f, 0.f, 0.f);
            if (colg >= 0 && colg <= W0 - 4)
                v = *(const float4*)(fr0 + ((size_t)(b * NC + c) * H0 + row) * W0 + colg);
            *(float4*)&frs0[rr][c][4 * q] = v;
        }
    }

    // ---- register-prefetch fl0: main cols (3 rows x 4 ch) + extra col ----
    const int wl = tid >> 3, g = tid & 7;        // phase-1 layout
    float flv0[3][4];
#pragma unroll
    for (int rr = 0; rr < 3; ++rr) {
        int row = min(max(m - 1 + rr, 0), H0 - 1);
#pragma unroll
        for (int j = 0; j < 4; ++j)
            flv0[rr][j] = fl0[((size_t)(b * NC + 8 * j + g) * H0 + row) * W0 + colp + wl];
    }
    float flv0e[3][4];
    if (tid < 8) {
#pragma unroll
        for (int rr = 0; rr < 3; ++rr) {
            int row = min(max(m - 1 + rr, 0), H0 - 1);
#pragma unroll
            for (int j = 0; j < 4; ++j)
                flv0e[rr][j] = fl0[((size_t)(b * NC + 8 * j + g) * H0 + row) * W0 + colp + 64];
        }
    }

    // ---- stage fr1: 2 rows x 32 ch x 42 float4 (zero OOB/pad) ----
#pragma unroll
    for (int i = 0; i < 6; ++i) {
        int idx = i * 512 + tid;
        if (idx < 2688) {
            int it = idx / 1344, rem = idx - it * 1344;
            int c = rem / 42, q = rem - c * 42;
            int colg = s1c0 + 4 * q;
            float4 v = make_float4(0.f, 0.f, 0.f, 0.f);
            if (colg >= 0 && colg <= W1 - 4)
                v = *(const float4*)(fr1 + ((size_t)(b * NC + c) * H1 + 2 * m + it) * W1 + colg);
            *(float4*)&frs1[it][c][4 * q] = v;
        }
    }

    // ---- register-prefetch fl1 (2 rows x 8 ch) ----
    const int oxl = tid >> 2, sub = tid & 3;     // phase-2 layout
    const int w1 = xh * 128 + oxl;
    float flv1[2][8];
#pragma unroll
    for (int it = 0; it < 2; ++it)
#pragma unroll
        for (int j = 0; j < 8; ++j)
            flv1[it][j] = fl1[((size_t)(b * NC + 4 * j + sub) * H1 + 2 * m + it) * W1 + w1];

    __syncthreads();

    // ---- phase 1: three pl0 rows over 65 cols (main 64 + extra 1) ----
#pragma unroll
    for (int rr = 0; rr < 3; ++rr) {
        float cost[D0];
#pragma unroll
        for (int d = 0; d < D0; ++d) cost[d] = 0.f;
#pragma unroll
        for (int j = 0; j < 4; ++j) {
            const float* sr = &frs0[rr][8 * j + g][16 - xh + wl];
            float fv = flv0[rr][j];
#pragma unroll
            for (int d = 0; d < D0; ++d)
                cost[d] += fabsf(fv - sr[-d]);
        }
#pragma unroll
        for (int d = 0; d < D0; ++d) {
            cost[d] += __shfl_xor(cost[d], 1);
            cost[d] += __shfl_xor(cost[d], 2);
            cost[d] += __shfl_xor(cost[d], 4);
        }
        if (g == 0) {
            float mn = cost[0];
#pragma unroll
            for (int d = 1; d < D0; ++d) mn = fminf(mn, cost[d]);
            float s = 0.f, sd = 0.f;
#pragma unroll
            for (int d = 0; d < D0; ++d) {
                float e = expf(mn - cost[d]);
                s += e;
                sd += (float)d * e;
            }
            float val = 8.f * (sd / s);
            p0l[rr][wl] = val;
            if (rr == 1)
                pl0[((size_t)b * H0 + m) * W0 + colp + wl] = val;
        }
    }
    if (tid < 8) {                       // extra col wl=64 (g = tid)
#pragma unroll
        for (int rr = 0; rr < 3; ++rr) {
            float cost[D0];
#pragma unroll
            for (int d = 0; d < D0; ++d) cost[d] = 0.f;
#pragma unroll
            for (int j = 0; j < 4; ++j) {
                const float* sr = &frs0[rr][8 * j + g][16 - xh + 64];
                float fv = flv0e[rr][j];
#pragma unroll
                for (int d = 0; d < D0; ++d)
                    cost[d] += fabsf(fv - sr[-d]);
            }
#pragma unroll
            for (int d = 0; d < D0; ++d) {
                cost[d] += __shfl_xor(cost[d], 1);
                cost[d] += __shfl_xor(cost[d], 2);
                cost[d] += __shfl_xor(cost[d], 4);
            }
            if (g == 0) {
                float mn = cost[0];
#pragma unroll
                for (int d = 1; d < D0; ++d) mn = fminf(mn, cost[d]);
                float s = 0.f, sd = 0.f;
#pragma unroll
                for (int d = 0; d < D0; ++d) {
                    float e = expf(mn - cost[d]);
                    s += e;
                    sd += (float)d * e;
                }
                float val = 8.f * (sd / s);
                p0l[rr][64] = val;
                if (rr == 1)
                    pl0[((size_t)b * H0 + m) * W0 + colp + 64] = val;
            }
        }
    }
    __syncthreads();

    // ---- y-composite into ytmp (2 x 65) ----
    if (tid < 256 && (tid & 127) < 65) {
        int it = tid >> 7, q = tid & 127;
        int oy = 2 * m + it;
        float wy0, wy1, wy2;
        if (oy == 0)           { wy0 = 0.f;           wy1 = 27.625f / 28.f; wy2 = 0.375f / 28.f; }
        else if (oy == H1 - 1) { wy0 = 0.375f / 28.f; wy1 = 27.625f / 28.f; wy2 = 0.f; }
        else if (oy & 1)       { wy0 = 0.375f / 32.f; wy1 = 23.25f / 32.f;  wy2 = 8.375f / 32.f; }
        else                   { wy0 = 8.375f / 32.f; wy1 = 23.25f / 32.f;  wy2 = 0.375f / 32.f; }
        ytmp[it][q] = wy0 * p0l[0][q] + wy1 * p0l[1][q] + wy2 * p0l[2][q];
    }
    __syncthreads();

    // ---- x-composite into wfl (2 x 128) ----
    if (tid < 256) {
        int it = tid >> 7, ol = tid & 127;
        int ox = xh * 128 + ol;
        int n = ox >> 1;
        int c0l, c1l, c2l;
        float wx0, wx1, wx2;
        if (ox == 0) {
            c0l = 0; c1l = 0; c2l = 1;
            wx0 = 0.f; wx1 = 27.625f / 28.f; wx2 = 0.375f / 28.f;
        } else if (ox == W1 - 1) {
            c0l = 63; c1l = 64; c2l = 64;          // cols 126,127 local (xh=1)
            wx0 = 0.375f / 28.f; wx1 = 27.625f / 28.f; wx2 = 0.f;
        } else {
            c0l = max(n - 1, 0) - colp; c1l = n - colp; c2l = min(n + 1, W0 - 1) - colp;
            if (ox & 1) { wx0 = 0.375f / 32.f; wx1 = 23.25f / 32.f; wx2 = 8.375f / 32.f; }
            else        { wx0 = 8.375f / 32.f; wx1 = 23.25f / 32.f; wx2 = 0.375f / 32.f; }
        }
        wfl[it][ol] = 0.25f * (wx0 * ytmp[it][c0l] + wx1 * ytmp[it][c1l]
                             + wx2 * ytmp[it][c2l]);
    }
    __syncthreads();

    // ---- phase 2: residual cost, shared-frac 6-tap window, both rows ----
#pragma unroll
    for (int it = 0; it < 2; ++it) {
        float disp = wfl[it][oxl];
        float xs = (float)w1 - disp;
        float xbf = floorf(xs);
        float f = xs - xbf;
        int xb = (int)xbf;                         // in [w1-23, w1]
        const float* sr = &frs1[it][0][xb - xh * 128 + 26];

        float cost[NK];
#pragma unroll
        for (int k = 0; k < NK; ++k) cost[k] = 0.f;
#pragma unroll
        for (int j = 0; j < 8; ++j) {
            const float* row = sr + (4 * j + sub) * S1L;
            float g0 = row[0], g1 = row[1], g2 = row[2];
            float g3 = row[3], g4 = row[4], g5 = row[5];
            float fv = flv1[it][j];
            cost[0] += fabsf(fv - (g0 + f * (g1 - g0)));
            cost[1] += fabsf(fv - (g1 + f * (g2 - g1)));
            cost[2] += fabsf(fv - (g2 + f * (g3 - g2)));
            cost[3] += fabsf(fv - (g3 + f * (g4 - g3)));
            cost[4] += fabsf(fv - (g5 * f + g4 * (1.f - f)));
        }
#pragma unroll
        for (int k = 0; k < NK; ++k) {
            cost[k] += __shfl_xor(cost[k], 1);
            cost[k] += __shfl_xor(cost[k], 2);
        }
        if (sub == 0) {
            float mn = cost[0];
#pragma unroll
            for (int k = 1; k < NK; ++k) mn = fminf(mn, cost[k]);
            float s = 0.f, sd = 0.f;
#pragma unroll
            for (int k = 0; k < NK; ++k) {
                float e = expf(mn - cost[k]);
                s += e;
                sd += (float)(k - 2) * e;
            }
            pl1[((size_t)b * H1 + 2 * m + it) * W1 + w1] = 4.f * (sd / s);
        }
    }
}

// ---------------------------------------------------------------------------
// K2: final — separable dual upsample, one block per output row. Write-bound.
// ---------------------------------------------------------------------------
__global__ __launch_bounds__(256, 4) void k_final(const float* __restrict__ pl0,
                                                  const float* __restrict__ pl1,
                                                  float* __restrict__ out) {
    const int blk = blockIdx.x;            // b*IMH + y
    const int b = blk >> 9, y = blk & (IMH - 1);
    const int tid = threadIdx.x;
    __shared__ float a0[W0];
    __shared__ float a1[W1];

    const float* p0b = pl0 + (size_t)b * H0 * W0;
    const float* p1b = pl1 + (size_t)b * H1 * W1;

    float sy0 = (y + 0.5f) * 0.125f - 0.5f;
    float y0f = floorf(sy0);
    float fy0 = sy0 - y0f;
    int r0 = (int)y0f;
    int r0c = min(max(r0, 0), H0 - 1), r1c = min(max(r0 + 1, 0), H0 - 1);

    float sy1 = (y + 0.5f) * 0.25f - 0.5f;
    float y1f = floorf(sy1);
    float fy1 = sy1 - y1f;
    int s0 = (int)y1f;
    int s0c = min(max(s0, 0), H1 - 1), s1c = min(max(s0 + 1, 0), H1 - 1);

    if (tid < W0) {
        float u = p0b[r0c * W0 + tid], v = p0b[r1c * W0 + tid];
        a0[tid] = u + fy0 * (v - u);
    }
    {
        float u = p1b[s0c * W1 + tid], v = p1b[s1c * W1 + tid];
        a1[tid] = u + fy1 * (v - u);
    }
    __syncthreads();

    float v0[4], v1[4];
#pragma unroll
    for (int i = 0; i < 4; ++i) {
        int x = tid * 4 + i;
        float sx0 = (x + 0.5f) * 0.125f - 0.5f;
        float x0f = floorf(sx0);
        float fx0 = sx0 - x0f;
        int c0 = (int)x0f;
        int c0c = min(max(c0, 0), W0 - 1), c1c = min(max(c0 + 1, 0), W0 - 1);
        float p0 = a0[c0c] + fx0 * (a0[c1c] - a0[c0c]);

        float sx1 = (x + 0.5f) * 0.25f - 0.5f;
        float x1f = floorf(sx1);
        float fx1 = sx1 - x1f;
        int d0 = (int)x1f;
        int d0c = min(max(d0, 0), W1 - 1), d1c = min(max(d0 + 1, 0), W1 - 1);
        float p1 = a1[d0c] + fx1 * (a1[d1c] - a1[d0c]);

        v0[i] = p0;
        v1[i] = p1 + p0;
    }
    const size_t NPXQ = (size_t)NB * IMH * IMW / 4;
    size_t t = (size_t)blk * 256 + tid;
    ((float4*)out)[t] = make_float4(v0[0], v0[1], v0[2], v0[3]);
    ((float4*)out)[NPXQ + t] = make_float4(v1[0], v1[1], v1[2], v1[3]);
}

// ---------------------------------------------------------------------------
extern "C" void kernel_launch(void* const* d_in, const int* in_sizes, int n_in,
                              void* d_out, int out_size, void* d_ws, size_t ws_size,
                              hipStream_t stream) {
    const float* fl0 = (const float*)d_in[0];
    const float* fr0 = (const float*)d_in[1];
    const float* fl1 = (const float*)d_in[2];
    const float* fr1 = (const float*)d_in[3];
    float* out = (float*)d_out;

    float* ws = (float*)d_ws;
    float* pl0 = ws;                 // 32768 floats
    float* pl1 = ws + 32768;         // 131072 floats

    k_main<<<NB * H0 * 2, 512, 0, stream>>>(fl0, fr0, fl1, fr1, pl0, pl1);
    k_final<<<NB * IMH, 256, 0, stream>>>(pl0, pl1, out);
}

// Round 11
// 26.393 us; speedup vs baseline: 1.3884x; 1.3884x over previous
//
#include <hip/hip_runtime.h>

#define NB 4
#define NC 32
#define H0 64
#define W0 128
#define D0 12
#define H1 128
#define W1 256
#define NK 5
#define IMH 512
#define IMW 1024

#define S0 144   // frs0 stride: 16 guard + 128 data (16B-aligned)
#define G0 16
#define S1 288   // frs1 stride: 28 guard + 256 data + 4 right guard
#define G1 28

// ---------------------------------------------------------------------------
// K1: scale-0 cost volume + regression. 256 blocks (one row) x 256 threads.
// Thread = (w, half): 16 channels each, ONE shfl_xor level. Minimal LDS ops.
// ---------------------------------------------------------------------------
__global__ __launch_bounds__(256) void k_cost0(const float* __restrict__ fl,
                                               const float* __restrict__ fr,
                                               float* __restrict__ pl0) {
    const int blk = blockIdx.x;          // b*H0 + h
    const int b = blk >> 6, h = blk & (H0 - 1);
    const int tid = threadIdx.x;
    const int w = tid >> 1, half = tid & 1;
    __shared__ float frs[NC][S0];        // 18 KB

    const size_t rowbase = ((size_t)b * NC * H0 + h) * W0;

    // prefetch fl: 16 channels c = 16*half + j
    float flv[16];
#pragma unroll
    for (int j = 0; j < 16; ++j)
        flv[j] = fl[rowbase + (size_t)(16 * half + j) * (H0 * W0) + w];

    // stage fr row: 1024 float4 (4/thread) + 128 guard float4
#pragma unroll
    for (int i = 0; i < 4; ++i) {
        int idx = i * 256 + tid;
        int c = idx >> 5, q = idx & 31;
        *(float4*)&frs[c][G0 + q * 4] =
            *(const float4*)(fr + rowbase + (size_t)c * (H0 * W0) + q * 4);
    }
    if (tid < 128) {
        int c = tid >> 2, u = tid & 3;
        *(float4*)&frs[c][u * 4] = make_float4(0.f, 0.f, 0.f, 0.f);
    }
    __syncthreads();

    float cost[D0];
#pragma unroll
    for (int d = 0; d < D0; ++d) cost[d] = 0.f;
#pragma unroll
    for (int j = 0; j < 16; ++j) {
        const float* sr = &frs[16 * half + j][G0 + w];
        float fv = flv[j];
#pragma unroll
        for (int d = 0; d < D0; ++d)
            cost[d] += fabsf(fv - sr[-d]);
    }
#pragma unroll
    for (int d = 0; d < D0; ++d)
        cost[d] += __shfl_xor(cost[d], 1);

    if (half == 0) {
        float mn = cost[0];
#pragma unroll
        for (int d = 1; d < D0; ++d) mn = fminf(mn, cost[d]);
        float s = 0.f, sd = 0.f;
#pragma unroll
        for (int d = 0; d < D0; ++d) {
            float e = expf(mn - cost[d]);
            s += e;
            sd += (float)d * e;
        }
        pl0[(size_t)blk * W0 + w] = 8.f * (sd / s);
    }
}

// ---------------------------------------------------------------------------
// K2: fused wflow (exact 3x3 composite) + residual cost volume + regression.
// 512 blocks (one row) x 256 threads. Thread = one column, ALL 32 channels:
// zero shuffles. fl1 register-prefetched before the barrier.
// ---------------------------------------------------------------------------
__global__ __launch_bounds__(256) void k_cost1(const float* __restrict__ fl,
                                               const float* __restrict__ fr,
                                               const float* __restrict__ pl0,
                                               float* __restrict__ pl1) {
    const int blk = blockIdx.x;          // b*H1 + oy
    const int b = blk >> 7, oy = blk & (H1 - 1);
    const int tid = threadIdx.x;         // = ox
    __shared__ float frs1[NC][S1];       // 36 KB
    __shared__ float ytmp[W0];
    __shared__ float wfl[W1];

    const size_t rowbase1 = ((size_t)b * NC * H1 + oy) * W1;

    // prefetch fl1: all 32 channels at this column
    float flv[32];
#pragma unroll
    for (int c = 0; c < NC; ++c)
        flv[c] = fl[rowbase1 + (size_t)c * (H1 * W1) + tid];

    // stage fr1 row: 2048 float4 (8/thread) + 256 guard float4 (1/thread)
#pragma unroll
    for (int i = 0; i < 8; ++i) {
        int idx = i * 256 + tid;
        int c = idx >> 6, q = idx & 63;
        *(float4*)&frs1[c][G1 + q * 4] =
            *(const float4*)(fr + rowbase1 + (size_t)c * (H1 * W1) + q * 4);
    }
    {
        int c = tid >> 3, u = tid & 7;
        int col = (u < 7) ? u * 4 : (G1 + W1);
        *(float4*)&frs1[c][col] = make_float4(0.f, 0.f, 0.f, 0.f);
    }

    // phase A: y-composite of pl0 into ytmp
    if (tid < W0) {
        const float* p0b = pl0 + (size_t)b * H0 * W0;
        int m = oy >> 1;
        int r0, r1, r2;
        float wy0, wy1, wy2;
        if (oy == 0) {
            r0 = 0; r1 = 0; r2 = 1;
            wy0 = 0.f; wy1 = 27.625f / 28.f; wy2 = 0.375f / 28.f;
        } else if (oy == H1 - 1) {
            r0 = H0 - 2; r1 = H0 - 1; r2 = H0 - 1;
            wy0 = 0.375f / 28.f; wy1 = 27.625f / 28.f; wy2 = 0.f;
        } else {
            r0 = max(m - 1, 0); r1 = m; r2 = min(m + 1, H0 - 1);
            if (oy & 1) { wy0 = 0.375f / 32.f; wy1 = 23.25f / 32.f; wy2 = 8.375f / 32.f; }
            else        { wy0 = 8.375f / 32.f; wy1 = 23.25f / 32.f; wy2 = 0.375f / 32.f; }
        }
        ytmp[tid] = wy0 * p0b[r0 * W0 + tid] + wy1 * p0b[r1 * W0 + tid]
                  + wy2 * p0b[r2 * W0 + tid];
    }
    __syncthreads();

    // phase B: x-composite into wfl
    {
        int ox = tid, n = ox >> 1;
        int c0, c1, c2;
        float wx0, wx1, wx2;
        if (ox == 0) {
            c0 = 0; c1 = 0; c2 = 1;
            wx0 = 0.f; wx1 = 27.625f / 28.f; wx2 = 0.375f / 28.f;
        } else if (ox == W1 - 1) {
            c0 = W0 - 2; c1 = W0 - 1; c2 = W0 - 1;
            wx0 = 0.375f / 28.f; wx1 = 27.625f / 28.f; wx2 = 0.f;
        } else {
            c0 = max(n - 1, 0); c1 = n; c2 = min(n + 1, W0 - 1);
            if (ox & 1) { wx0 = 0.375f / 32.f; wx1 = 23.25f / 32.f; wx2 = 8.375f / 32.f; }
            else        { wx0 = 8.375f / 32.f; wx1 = 23.25f / 32.f; wx2 = 0.375f / 32.f; }
        }
        wfl[ox] = 0.25f * (wx0 * ytmp[c0] + wx1 * ytmp[c1] + wx2 * ytmp[c2]);
    }
    __syncthreads();   // wfl ready; frs1 staging complete

    // phase C: residual cost, shared-frac 6-tap window, all 32 channels
    {
        float disp = wfl[tid];
        float xs = (float)tid - disp;
        float xbf = floorf(xs);
        float f = xs - xbf;
        int xb = (int)xbf;                 // in [tid-23, tid]
        const float* sr = &frs1[0][G1 + xb - 2];

        float cost[NK];
#pragma unroll
        for (int k = 0; k < NK; ++k) cost[k] = 0.f;
#pragma unroll
        for (int c = 0; c < NC; ++c) {
            const float* row = sr + c * S1;
            float g0 = row[0], g1 = row[1], g2 = row[2];
            float g3 = row[3], g4 = row[4], g5 = row[5];
            float fv = flv[c];
            cost[0] += fabsf(fv - (g0 + f * (g1 - g0)));
            cost[1] += fabsf(fv - (g1 + f * (g2 - g1)));
            cost[2] += fabsf(fv - (g2 + f * (g3 - g2)));
            cost[3] += fabsf(fv - (g3 + f * (g4 - g3)));
            cost[4] += fabsf(fv - (g5 * f + g4 * (1.f - f)));
        }
        float mn = cost[0];
#pragma unroll
        for (int k = 1; k < NK; ++k) mn = fminf(mn, cost[k]);
        float s = 0.f, sd = 0.f;
#pragma unroll
        for (int k = 0; k < NK; ++k) {
            float e = expf(mn - cost[k]);
            s += e;
            sd += (float)(k - 2) * e;
        }
        pl1[(size_t)blk * W1 + tid] = 4.f * (sd / s);
    }
}

// ---------------------------------------------------------------------------
// K3: final — separable dual upsample, one block per output row. Write-bound.
// ---------------------------------------------------------------------------
__global__ __launch_bounds__(256, 4) void k_final(const float* __restrict__ pl0,
                                                  const float* __restrict__ pl1,
                                                  float* __restrict__ out) {
    const int blk = blockIdx.x;            // b*IMH + y
    const int b = blk >> 9, y = blk & (IMH - 1);
    const int tid = threadIdx.x;
    __shared__ float a0[W0];
    __shared__ float a1[W1];

    const float* p0b = pl0 + (size_t)b * H0 * W0;
    const float* p1b = pl1 + (size_t)b * H1 * W1;

    float sy0 = (y + 0.5f) * 0.125f - 0.5f;
    float y0f = floorf(sy0);
    float fy0 = sy0 - y0f;
    int r0 = (int)y0f;
    int r0c = min(max(r0, 0), H0 - 1), r1c = min(max(r0 + 1, 0), H0 - 1);

    float sy1 = (y + 0.5f) * 0.25f - 0.5f;
    float y1f = floorf(sy1);
    float fy1 = sy1 - y1f;
    int s0 = (int)y1f;
    int s0c = min(max(s0, 0), H1 - 1), s1c = min(max(s0 + 1, 0), H1 - 1);

    if (tid < W0) {
        float u = p0b[r0c * W0 + tid], v = p0b[r1c * W0 + tid];
        a0[tid] = u + fy0 * (v - u);
    }
    {
        float u = p1b[s0c * W1 + tid], v = p1b[s1c * W1 + tid];
        a1[tid] = u + fy1 * (v - u);
    }
    __syncthreads();

    float v0[4], v1[4];
#pragma unroll
    for (int i = 0; i < 4; ++i) {
        int x = tid * 4 + i;
        float sx0 = (x + 0.5f) * 0.125f - 0.5f;
        float x0f = floorf(sx0);
        float fx0 = sx0 - x0f;
        int c0 = (int)x0f;
        int c0c = min(max(c0, 0), W0 - 1), c1c = min(max(c0 + 1, 0), W0 - 1);
        float p0 = a0[c0c] + fx0 * (a0[c1c] - a0[c0c]);

        float sx1 = (x + 0.5f) * 0.25f - 0.5f;
        float x1f = floorf(sx1);
        float fx1 = sx1 - x1f;
        int d0 = (int)x1f;
        int d0c = min(max(d0, 0), W1 - 1), d1c = min(max(d0 + 1, 0), W1 - 1);
        float p1 = a1[d0c] + fx1 * (a1[d1c] - a1[d0c]);

        v0[i] = p0;
        v1[i] = p1 + p0;
    }
    const size_t NPXQ = (size_t)NB * IMH * IMW / 4;
    size_t t = (size_t)blk * 256 + tid;
    ((float4*)out)[t] = make_float4(v0[0], v0[1], v0[2], v0[3]);
    ((float4*)out)[NPXQ + t] = make_float4(v1[0], v1[1], v1[2], v1[3]);
}

// ---------------------------------------------------------------------------
extern "C" void kernel_launch(void* const* d_in, const int* in_sizes, int n_in,
                              void* d_out, int out_size, void* d_ws, size_t ws_size,
                              hipStream_t stream) {
    const float* fl0 = (const float*)d_in[0];
    const float* fr0 = (const float*)d_in[1];
    const float* fl1 = (const float*)d_in[2];
    const float* fr1 = (const float*)d_in[3];
    float* out = (float*)d_out;

    float* ws = (float*)d_ws;
    float* pl0 = ws;                 // 32768 floats
    float* pl1 = ws + 32768;         // 131072 floats

    k_cost0<<<NB * H0, 256, 0, stream>>>(fl0, fr0, pl0);
    k_cost1<<<NB * H1, 256, 0, stream>>>(fl1, fr1, pl0, pl1);
    k_final<<<NB * IMH, 256, 0, stream>>>(pl0, pl1, out);
}